// Round 4
// baseline (44.959 us; speedup 1.0000x reference)
//
#include <hip/hip_runtime.h>
#include <hip/hip_bf16.h>

#define Nn 8192
#define Mm 1024
#define Dd 1024

typedef __attribute__((ext_vector_type(8))) short short8;
typedef __attribute__((ext_vector_type(4))) short short4v;
typedef __attribute__((ext_vector_type(4))) float f32x4;

typedef const __attribute__((address_space(1))) void* gas_p;
typedef __attribute__((address_space(3))) void* las_p;

// round-to-nearest-even fp32 -> bf16 (bit pattern as short)
__device__ __forceinline__ short f2bf(float f) {
  unsigned u = __builtin_bit_cast(unsigned, f);
  u += 0x7fffu + ((u >> 16) & 1u);
  return (short)(u >> 16);
}

// ---------------- kernel 1: h (fp32) -> A (bf16) ----------------
__global__ void conv_h_kernel(const float* __restrict__ h, short* __restrict__ A) {
  long i = (long)blockIdx.x * blockDim.x + threadIdx.x; // 8 elems per thread
  const float4* h4 = (const float4*)h;
  float4 a = h4[2 * i];
  float4 b = h4[2 * i + 1];
  short8 o;
  o[0] = f2bf(a.x); o[1] = f2bf(a.y); o[2] = f2bf(a.z); o[3] = f2bf(a.w);
  o[4] = f2bf(b.x); o[5] = f2bf(b.y); o[6] = f2bf(b.z); o[7] = f2bf(b.w);
  *(short8*)(A + 8 * i) = o;
}

// ---------------- kernel 2: B'[m,d] = bf16(u*w3 + w1); c[m] = u . w2 ----------------
__global__ void prep_b_kernel(const float* __restrict__ u, const float* __restrict__ w,
                              short* __restrict__ Bp, float* __restrict__ cvec) {
  int m = blockIdx.x;      // 1024 blocks
  int t = threadIdx.x;     // 256 threads, 4 elems each
  float4 uv = ((const float4*)(u + (size_t)m * Dd))[t];
  float4 w1 = ((const float4*)(w))[t];
  float4 w2 = ((const float4*)(w + Dd))[t];
  float4 w3 = ((const float4*)(w + 2 * Dd))[t];
  float p = uv.x * w2.x + uv.y * w2.y + uv.z * w2.z + uv.w * w2.w;
  short4v o;
  o[0] = f2bf(fmaf(uv.x, w3.x, w1.x));
  o[1] = f2bf(fmaf(uv.y, w3.y, w1.y));
  o[2] = f2bf(fmaf(uv.z, w3.z, w1.z));
  o[3] = f2bf(fmaf(uv.w, w3.w, w1.w));
  *(short4v*)(Bp + (size_t)m * Dd + t * 4) = o;

#pragma unroll
  for (int off = 32; off > 0; off >>= 1) p += __shfl_down(p, off);
  __shared__ float sred[4];
  if ((t & 63) == 0) sred[t >> 6] = p;
  __syncthreads();
  if (t == 0) cvec[m] = sred[0] + sred[1] + sred[2] + sred[3];
}

// ---------------- kernel 3: GEMM  S = A @ B'^T + c ----------------
// Tile 256x128, BK=64, 512 threads = 8 waves (4M x 2N), wave 64x64 out.
// 8-phase-style fine interleave (T3+T4+T5): 4 phases per K-tile, each
// {ds_read k-slice frags; issue staging; s_barrier; lgkmcnt(0)+sched_barrier;
//  setprio(1) 8xMFMA setprio(0); s_barrier}.
// A triple-buffered (depth-2 prefetch, 96KB), B double-buffered (depth-1,
// issued FIRST each tile, 32KB) -> 128KB LDS. Boundary s_waitcnt vmcnt(4):
// per-tile issue order [B(kt+1) x2, A(kt+2) x4] => 4 newest = A(kt+2);
// everything older (A(kt+1), B(kt+1)) complete. Never drains in main loop.
// XOR swizzle byte ^= ((row&7)<<4) both-sides (pre-swizzled global src for
// global_load_lds linear dest; swizzled ds_read addr).
__global__ __launch_bounds__(512) void gemm_kernel(
    const short* __restrict__ A,   // N x D bf16
    const short* __restrict__ B,   // M x D bf16 (B')
    const float* __restrict__ cvec,// M
    float* __restrict__ out)       // N x M fp32
{
  __shared__ __align__(16) short As[3][256 * 64];  // 96 KB
  __shared__ __align__(16) short Bs[2][128 * 64];  // 32 KB

  const int bid = blockIdx.x;
  // bijective XCD swizzle: 256 blocks, 32 per XCD
  const int swz  = (bid & 7) * 32 + (bid >> 3);
  const int brow = swz >> 3;   // 0..31
  const int bcol = swz & 7;    // 0..7

  const int tid  = threadIdx.x;
  const int lane = tid & 63;
  const int wid  = tid >> 6;

  const int l8 = lane >> 3;                // row within 8-row group
  const int kc = (lane & 7) ^ l8;          // pre-swizzled global 16B-chunk index
  const short* Ag = A + (size_t)(brow * 256 + wid * 32 + l8) * Dd + kc * 8;
  const short* Bg = B + (size_t)(bcol * 128 + wid * 16 + l8) * Dd + kc * 8;
  const int AsOff = (wid * 32) * 64;
  const int BsOff = (wid * 16) * 64;

  const int wr = wid >> 1, wc = wid & 1;   // 4 x 2 wave grid
  const int arow0 = wr * 64 + (lane & 15);
  const int brow0 = wc * 64 + (lane & 15);
  const int kb = (lane >> 4) * 16;         // byte offset of 16B chunk in 64B k-slice
  const int sw = (lane & 7) << 4;          // read-side XOR (row&7)<<4

  f32x4 acc[4][4] = {};
  short8 af0, af1, bf0, bf1, bf2, bf3;

#define GLOAD(gp, lp) __builtin_amdgcn_global_load_lds((gas_p)(gp), (las_p)(lp), 16, 0, 0)

#define STAGE_A2(buf, kt, half) do { \
    GLOAD(Ag + (size_t)(kt) * 64 + ((half) * 2 + 0) * 8 * Dd, &As[buf][AsOff + ((half) * 2 + 0) * 8 * 64]); \
    GLOAD(Ag + (size_t)(kt) * 64 + ((half) * 2 + 1) * 8 * Dd, &As[buf][AsOff + ((half) * 2 + 1) * 8 * 64]); \
  } while (0)

#define STAGE_B2(buf, kt) do { \
    GLOAD(Bg + (size_t)(kt) * 64 + 0 * 8 * Dd, &Bs[buf][BsOff + 0 * 8 * 64]); \
    GLOAD(Bg + (size_t)(kt) * 64 + 1 * 8 * Dd, &Bs[buf][BsOff + 1 * 8 * 64]); \
  } while (0)

#define RD_A(cura, kk, ih) do { \
    const char* ba_ = (const char*)&As[cura][0]; \
    const int ko_ = (kk) * 64 + kb; \
    af0 = *(const short8*)(ba_ + ((arow0 + ((ih) * 2 + 0) * 16) * 128 + (ko_ ^ sw))); \
    af1 = *(const short8*)(ba_ + ((arow0 + ((ih) * 2 + 1) * 16) * 128 + (ko_ ^ sw))); \
  } while (0)

#define RD_B(curb, kk) do { \
    const char* bb_ = (const char*)&Bs[curb][0]; \
    const int ko_ = (kk) * 64 + kb; \
    bf0 = *(const short8*)(bb_ + ((brow0 +  0) * 128 + (ko_ ^ sw))); \
    bf1 = *(const short8*)(bb_ + ((brow0 + 16) * 128 + (ko_ ^ sw))); \
    bf2 = *(const short8*)(bb_ + ((brow0 + 32) * 128 + (ko_ ^ sw))); \
    bf3 = *(const short8*)(bb_ + ((brow0 + 48) * 128 + (ko_ ^ sw))); \
  } while (0)

#define MFMA8(ih) do { \
    __builtin_amdgcn_s_setprio(1); \
    acc[(ih)*2+0][0] = __builtin_amdgcn_mfma_f32_16x16x32_bf16(af0, bf0, acc[(ih)*2+0][0], 0, 0, 0); \
    acc[(ih)*2+0][1] = __builtin_amdgcn_mfma_f32_16x16x32_bf16(af0, bf1, acc[(ih)*2+0][1], 0, 0, 0); \
    acc[(ih)*2+0][2] = __builtin_amdgcn_mfma_f32_16x16x32_bf16(af0, bf2, acc[(ih)*2+0][2], 0, 0, 0); \
    acc[(ih)*2+0][3] = __builtin_amdgcn_mfma_f32_16x16x32_bf16(af0, bf3, acc[(ih)*2+0][3], 0, 0, 0); \
    acc[(ih)*2+1][0] = __builtin_amdgcn_mfma_f32_16x16x32_bf16(af1, bf0, acc[(ih)*2+1][0], 0, 0, 0); \
    acc[(ih)*2+1][1] = __builtin_amdgcn_mfma_f32_16x16x32_bf16(af1, bf1, acc[(ih)*2+1][1], 0, 0, 0); \
    acc[(ih)*2+1][2] = __builtin_amdgcn_mfma_f32_16x16x32_bf16(af1, bf2, acc[(ih)*2+1][2], 0, 0, 0); \
    acc[(ih)*2+1][3] = __builtin_amdgcn_mfma_f32_16x16x32_bf16(af1, bf3, acc[(ih)*2+1][3], 0, 0, 0); \
    __builtin_amdgcn_s_setprio(0); \
  } while (0)

#define BARRIER __builtin_amdgcn_s_barrier()
#define LGKM0   asm volatile("s_waitcnt lgkmcnt(0)" ::: "memory")
#define SCHED0  __builtin_amdgcn_sched_barrier(0)

// 4 phases per K-tile; staging statements injected into phases 0/1
#define TILE(cura, curb, SB, SA0, SA1) do { \
    RD_A(cura, 0, 0); RD_B(curb, 0); \
    SB; SA0; \
    BARRIER; LGKM0; SCHED0; MFMA8(0); BARRIER; \
    RD_A(cura, 0, 1); \
    SA1; \
    BARRIER; LGKM0; SCHED0; MFMA8(1); BARRIER; \
    RD_A(cura, 1, 0); RD_B(curb, 1); \
    BARRIER; LGKM0; SCHED0; MFMA8(0); BARRIER; \
    RD_A(cura, 1, 1); \
    BARRIER; LGKM0; SCHED0; MFMA8(1); \
  } while (0)

  const int NT = Dd / 64;  // 16 K-tiles

  // prologue: A(0)->As[0], B(0)->Bs[0], A(1)->As[1]  (10 loads in flight)
  STAGE_A2(0, 0, 0); STAGE_A2(0, 0, 1);
  STAGE_B2(0, 0);
  STAGE_A2(1, 1, 0); STAGE_A2(1, 1, 1);
  asm volatile("s_waitcnt vmcnt(4)" ::: "memory");  // A(0)+B(0) complete; A(1) in flight
  BARRIER;

  int cur3 = 0, astg = 2, bcur = 0;
#pragma unroll 1
  for (int kt = 0; kt < NT - 2; ++kt) {
    TILE(cur3, bcur,
         STAGE_B2(bcur ^ 1, kt + 1),
         STAGE_A2(astg, kt + 2, 0),
         STAGE_A2(astg, kt + 2, 1));
    asm volatile("s_waitcnt vmcnt(4)" ::: "memory");  // keep only A(kt+2) in flight
    BARRIER;
    cur3 = (cur3 == 2) ? 0 : cur3 + 1;
    astg = (astg == 2) ? 0 : astg + 1;
    bcur ^= 1;
  }
  // kt = NT-2: stage B(NT-1) only
  TILE(cur3, bcur, STAGE_B2(bcur ^ 1, NT - 1), (void)0, (void)0);
  asm volatile("s_waitcnt vmcnt(0)" ::: "memory");
  BARRIER;
  cur3 = (cur3 == 2) ? 0 : cur3 + 1;
  bcur ^= 1;
  // kt = NT-1: no staging
  TILE(cur3, bcur, (void)0, (void)0, (void)0);

  // --- epilogue: S[n,m] = acc + c[m] ---
  const int n0 = brow * 256 + wr * 64 + (lane >> 4) * 4;
  const int m0 = bcol * 128 + wc * 64 + (lane & 15);
#pragma unroll
  for (int j = 0; j < 4; ++j) {
    const float cm = cvec[m0 + j * 16];
#pragma unroll
    for (int i = 0; i < 4; ++i) {
      float* op = out + (size_t)(n0 + i * 16) * Mm + m0 + j * 16;
#pragma unroll
      for (int r = 0; r < 4; ++r)
        op[(size_t)r * Mm] = acc[i][j][r] + cm;
    }
  }
#undef GLOAD
#undef STAGE_A2
#undef STAGE_B2
#undef RD_A
#undef RD_B
#undef MFMA8
#undef BARRIER
#undef LGKM0
#undef SCHED0
#undef TILE
}

extern "C" void kernel_launch(void* const* d_in, const int* in_sizes, int n_in,
                              void* d_out, int out_size, void* d_ws, size_t ws_size,
                              hipStream_t stream) {
  const float* h = (const float*)d_in[0];
  const float* u = (const float*)d_in[1];
  const float* w = (const float*)d_in[2];
  float* out = (float*)d_out;

  // workspace layout: A bf16 (16MB) | B' bf16 (2MB) | c fp32 (4KB)
  short* Abf = (short*)d_ws;
  short* Bp  = Abf + (size_t)Nn * Dd;
  float* cvec = (float*)(Bp + (size_t)Mm * Dd);

  conv_h_kernel<<<(Nn * Dd / 8) / 256, 256, 0, stream>>>(h, Abf);
  prep_b_kernel<<<Mm, 256, 0, stream>>>(u, w, Bp, cvec);
  gemm_kernel<<<(Nn / 256) * (Mm / 128), 512, 0, stream>>>(Abf, Bp, cvec, out);
}

// Round 5
// 38.069 us; speedup vs baseline: 1.1810x; 1.1810x over previous
//
#include <hip/hip_runtime.h>
#include <hip/hip_bf16.h>

#define Nn 8192
#define Mm 1024
#define Dd 1024

typedef __attribute__((ext_vector_type(8))) short short8;
typedef __attribute__((ext_vector_type(4))) short short4v;
typedef __attribute__((ext_vector_type(4))) float f32x4;
typedef __attribute__((ext_vector_type(2))) unsigned uint2v;

typedef const __attribute__((address_space(1))) void* gas_p;
typedef __attribute__((address_space(3))) void* las_p;

// round-to-nearest-even fp32 -> bf16 (bit pattern as short)
__device__ __forceinline__ short f2bf(float f) {
  unsigned u = __builtin_bit_cast(unsigned, f);
  u += 0x7fffu + ((u >> 16) & 1u);
  return (short)(u >> 16);
}

// packed RNE fp32x2 -> bf16x2 (hardware cvt; pure VALU, no mem hazard)
__device__ __forceinline__ unsigned cvt2bf(float lo, float hi) {
  unsigned r;
  asm("v_cvt_pk_bf16_f32 %0, %1, %2" : "=v"(r) : "v"(lo), "v"(hi));
  return r;
}

// ---------------- kernel 1: B'[m,d] = bf16(u*w3 + w1); c[m] = u . w2 ----------------
__global__ void prep_b_kernel(const float* __restrict__ u, const float* __restrict__ w,
                              short* __restrict__ Bp, float* __restrict__ cvec) {
  int m = blockIdx.x;      // 1024 blocks
  int t = threadIdx.x;     // 256 threads, 4 elems each
  float4 uv = ((const float4*)(u + (size_t)m * Dd))[t];
  float4 w1 = ((const float4*)(w))[t];
  float4 w2 = ((const float4*)(w + Dd))[t];
  float4 w3 = ((const float4*)(w + 2 * Dd))[t];
  float p = uv.x * w2.x + uv.y * w2.y + uv.z * w2.z + uv.w * w2.w;
  short4v o;
  o[0] = f2bf(fmaf(uv.x, w3.x, w1.x));
  o[1] = f2bf(fmaf(uv.y, w3.y, w1.y));
  o[2] = f2bf(fmaf(uv.z, w3.z, w1.z));
  o[3] = f2bf(fmaf(uv.w, w3.w, w1.w));
  *(short4v*)(Bp + (size_t)m * Dd + t * 4) = o;

#pragma unroll
  for (int off = 32; off > 0; off >>= 1) p += __shfl_down(p, off);
  __shared__ float sred[4];
  if ((t & 63) == 0) sred[t >> 6] = p;
  __syncthreads();
  if (t == 0) cvec[m] = sred[0] + sred[1] + sred[2] + sred[3];
}

// ---------------- kernel 2: fused GEMM  S = bf16(h) @ B'^T + c ----------------
// 128x128 tile, BK=64, 256 thr = 4 waves (2x2), wave 64x64 out (R0-proven math).
// A: fp32 loaded to REGISTERS (issued BEFORE compute -> latency hidden under
//    MFMA+ds_read), converted v_cvt_pk_bf16_f32, ds_write_b64 AFTER compute
//    into the other buffer (T14 issue-early/write-late). Write-side XOR swizzle
//    byte ^= ((row&7)<<4) applied directly on the ds_write address.
// B: global_load_lds (16B) with pre-swizzled global source, prefetched one
//    tile ahead into the other buffer (proven R0 path).
// One s_barrier per K-tile: vmcnt(0) (B staged + A regs consumed) + lgkmcnt(0)
// (my ds_writes + ds_reads retired) before it.
__global__ __launch_bounds__(256) void gemm_fused_kernel(
    const float* __restrict__ h,   // N x D fp32
    const short* __restrict__ B,   // M x D bf16 (B')
    const float* __restrict__ cvec,// M
    float* __restrict__ out)       // N x M fp32
{
  __shared__ __align__(16) short As[2][128 * 64];  // 32 KB
  __shared__ __align__(16) short Bs[2][128 * 64];  // 32 KB

  const int bid = blockIdx.x;
  // bijective XCD swizzle: 512 blocks, 64 per XCD; M-dim fastest within XCD
  const int swz  = (bid & 7) * 64 + (bid >> 3);
  const int brow = swz >> 3;   // 0..63
  const int bcol = swz & 7;    // 0..7

  const int tid  = threadIdx.x;
  const int lane = tid & 63;
  const int wid  = tid >> 6;

  // --- B staging (global_load_lds, pre-swizzled source) ---
  const int l8 = lane >> 3;
  const int kc = (lane & 7) ^ l8;
  const short* Bg = B + (size_t)(bcol * 128 + wid * 32 + l8) * Dd + kc * 8;
  const int BsOff = (wid * 32) * 64;

  // --- A reg-staging: thread t covers rows (t>>4)+16j (j=0..7), k-chunk (t&15)*4 floats ---
  const float* hg = h + (size_t)(brow * 128 + (tid >> 4)) * Dd + (tid & 15) * 4;
  const int awr   = tid >> 4;                       // base row 0..15
  const int axr   = (awr & 7) << 4;                 // write-side XOR (row&7)<<4 (16j keeps row&7)
  const int abyte0 = awr * 128 + (((tid & 15) * 8) ^ axr);

  // --- fragment reads (R0-proven) ---
  const int wr = wid >> 1, wc = wid & 1;
  const int arow0 = wr * 64 + (lane & 15);
  const int brow0 = wc * 64 + (lane & 15);
  const int kb = (lane >> 4) * 16;
  const int sw = (lane & 7) << 4;

  f32x4 acc[4][4] = {};
  const int NT = Dd / 64;  // 16 K-tiles

  // ---- prologue: stage tile 0 into buffer 0 ----
  {
#pragma unroll
    for (int j = 0; j < 4; ++j)
      __builtin_amdgcn_global_load_lds((gas_p)(Bg + j * 8 * Dd),
                                       (las_p)(&Bs[0][BsOff + j * 8 * 64]), 16, 0, 0);
    float4 av0 = *(const float4*)(hg + 0 * 16 * Dd);
    float4 av1 = *(const float4*)(hg + 1 * 16 * Dd);
    float4 av2 = *(const float4*)(hg + 2 * 16 * Dd);
    float4 av3 = *(const float4*)(hg + 3 * 16 * Dd);
    float4 av4 = *(const float4*)(hg + 4 * 16 * Dd);
    float4 av5 = *(const float4*)(hg + 5 * 16 * Dd);
    float4 av6 = *(const float4*)(hg + 6 * 16 * Dd);
    float4 av7 = *(const float4*)(hg + 7 * 16 * Dd);
    char* asb = (char*)&As[0][0] + abyte0;
    uint2v p;
    p[0] = cvt2bf(av0.x, av0.y); p[1] = cvt2bf(av0.z, av0.w); *(uint2v*)(asb + 0 * 2048) = p;
    p[0] = cvt2bf(av1.x, av1.y); p[1] = cvt2bf(av1.z, av1.w); *(uint2v*)(asb + 1 * 2048) = p;
    p[0] = cvt2bf(av2.x, av2.y); p[1] = cvt2bf(av2.z, av2.w); *(uint2v*)(asb + 2 * 2048) = p;
    p[0] = cvt2bf(av3.x, av3.y); p[1] = cvt2bf(av3.z, av3.w); *(uint2v*)(asb + 3 * 2048) = p;
    p[0] = cvt2bf(av4.x, av4.y); p[1] = cvt2bf(av4.z, av4.w); *(uint2v*)(asb + 4 * 2048) = p;
    p[0] = cvt2bf(av5.x, av5.y); p[1] = cvt2bf(av5.z, av5.w); *(uint2v*)(asb + 5 * 2048) = p;
    p[0] = cvt2bf(av6.x, av6.y); p[1] = cvt2bf(av6.z, av6.w); *(uint2v*)(asb + 6 * 2048) = p;
    p[0] = cvt2bf(av7.x, av7.y); p[1] = cvt2bf(av7.z, av7.w); *(uint2v*)(asb + 7 * 2048) = p;
    asm volatile("s_waitcnt vmcnt(0)" ::: "memory");
    asm volatile("s_waitcnt lgkmcnt(0)" ::: "memory");
    __builtin_amdgcn_s_barrier();
  }

  int cur = 0;
#pragma unroll 1
  for (int kt = 0; kt < NT; ++kt) {
    float4 av0, av1, av2, av3, av4, av5, av6, av7;
    const bool pf = (kt + 1 < NT);
    if (pf) {
      // issue next-tile B staging + A global loads BEFORE compute (latency hides)
      const short* Bgk = Bg + (kt + 1) * 64;
#pragma unroll
      for (int j = 0; j < 4; ++j)
        __builtin_amdgcn_global_load_lds((gas_p)(Bgk + j * 8 * Dd),
                                         (las_p)(&Bs[cur ^ 1][BsOff + j * 8 * 64]), 16, 0, 0);
      const float* ab = hg + (kt + 1) * 64;
      av0 = *(const float4*)(ab + 0 * 16 * Dd);
      av1 = *(const float4*)(ab + 1 * 16 * Dd);
      av2 = *(const float4*)(ab + 2 * 16 * Dd);
      av3 = *(const float4*)(ab + 3 * 16 * Dd);
      av4 = *(const float4*)(ab + 4 * 16 * Dd);
      av5 = *(const float4*)(ab + 5 * 16 * Dd);
      av6 = *(const float4*)(ab + 6 * 16 * Dd);
      av7 = *(const float4*)(ab + 7 * 16 * Dd);
    }
    // ---- compute current buffer (R0-proven) ----
#pragma unroll
    for (int kk = 0; kk < 2; ++kk) {
      short8 af[4], bfr[4];
      const int koff = kk * 64 + kb;
#pragma unroll
      for (int i = 0; i < 4; ++i) {
        af[i]  = *(const short8*)((const char*)&As[cur][0] + ((arow0 + i * 16) * 128 + (koff ^ sw)));
        bfr[i] = *(const short8*)((const char*)&Bs[cur][0] + ((brow0 + i * 16) * 128 + (koff ^ sw)));
      }
#pragma unroll
      for (int i = 0; i < 4; ++i)
#pragma unroll
        for (int j = 0; j < 4; ++j)
          acc[i][j] = __builtin_amdgcn_mfma_f32_16x16x32_bf16(af[i], bfr[j], acc[i][j], 0, 0, 0);
    }
    if (pf) {
      // convert + write A(kt+1) into the other buffer (readers of it finished last iter)
      char* asb = (char*)&As[cur ^ 1][0] + abyte0;
      uint2v p;
      p[0] = cvt2bf(av0.x, av0.y); p[1] = cvt2bf(av0.z, av0.w); *(uint2v*)(asb + 0 * 2048) = p;
      p[0] = cvt2bf(av1.x, av1.y); p[1] = cvt2bf(av1.z, av1.w); *(uint2v*)(asb + 1 * 2048) = p;
      p[0] = cvt2bf(av2.x, av2.y); p[1] = cvt2bf(av2.z, av2.w); *(uint2v*)(asb + 2 * 2048) = p;
      p[0] = cvt2bf(av3.x, av3.y); p[1] = cvt2bf(av3.z, av3.w); *(uint2v*)(asb + 3 * 2048) = p;
      p[0] = cvt2bf(av4.x, av4.y); p[1] = cvt2bf(av4.z, av4.w); *(uint2v*)(asb + 4 * 2048) = p;
      p[0] = cvt2bf(av5.x, av5.y); p[1] = cvt2bf(av5.z, av5.w); *(uint2v*)(asb + 5 * 2048) = p;
      p[0] = cvt2bf(av6.x, av6.y); p[1] = cvt2bf(av6.z, av6.w); *(uint2v*)(asb + 6 * 2048) = p;
      p[0] = cvt2bf(av7.x, av7.y); p[1] = cvt2bf(av7.z, av7.w); *(uint2v*)(asb + 7 * 2048) = p;
    }
    asm volatile("s_waitcnt vmcnt(0)" ::: "memory");   // B(kt+1) staged; A regs consumed
    asm volatile("s_waitcnt lgkmcnt(0)" ::: "memory"); // my ds_writes + ds_reads retired
    __builtin_amdgcn_s_barrier();
    cur ^= 1;
  }

  // --- epilogue: S[n,m] = acc + c[m] (R0-proven) ---
  const int n0 = brow * 128 + wr * 64 + (lane >> 4) * 4;
  const int m0 = bcol * 128 + wc * 64 + (lane & 15);
#pragma unroll
  for (int j = 0; j < 4; ++j) {
    const float cm = cvec[m0 + j * 16];
#pragma unroll
    for (int i = 0; i < 4; ++i) {
      float* op = out + (size_t)(n0 + i * 16) * Mm + m0 + j * 16;
#pragma unroll
      for (int r = 0; r < 4; ++r)
        op[(size_t)r * Mm] = acc[i][j][r] + cm;
    }
  }
}

extern "C" void kernel_launch(void* const* d_in, const int* in_sizes, int n_in,
                              void* d_out, int out_size, void* d_ws, size_t ws_size,
                              hipStream_t stream) {
  const float* h = (const float*)d_in[0];
  const float* u = (const float*)d_in[1];
  const float* w = (const float*)d_in[2];
  float* out = (float*)d_out;

  // workspace layout: B' bf16 (2MB) | c fp32 (4KB)
  short* Bp  = (short*)d_ws;
  float* cvec = (float*)(Bp + (size_t)Mm * Dd);

  prep_b_kernel<<<Mm, 256, 0, stream>>>(u, w, Bp, cvec);
  gemm_fused_kernel<<<(Nn / 128) * (Mm / 128), 256, 0, stream>>>(h, Bp, cvec, out);
}